// Round 8
// baseline (281.046 us; speedup 1.0000x reference)
//
#include <hip/hip_runtime.h>
#include <hip/hip_cooperative_groups.h>
#include <math.h>

namespace cg = cooperative_groups;

#define BB 8192
#define DD 2048
#define BN_EPS 1e-5f

// ---------------- cooperative fused path ----------------
#define NBLK 256
#define NTHR 512
#define RPB  32   // rows per block   (NBLK * RPB == BB)
#define CPT  4    // cols per thread  (NTHR * CPT == DD)
#define NWV  (NTHR / 64)

// Ledger of launch_bounds on this kernel family (empirical, gfx950):
//   (512,4) -> 64-VGPR cap: full spill, 640us
//   (512,1) -> 128-VGPR cap: half the 128-float v-tile spilled,
//              WRITE 138MB vs 80 expected, VALUBusy 2.9%, ~275-350us
//   (512)   -> free allocation (>128). With 512 threads the block must
//              stay launchable -> hard cap 256 VGPR -> 1 block/CU, which
//              is exactly the co-residency we need for 256 blocks.
// kernel_launch verifies >=1 block/CU via occupancy query before the coop
// launch (ROCm does NOT validate co-residency; oversubscription deadlocks).
__global__ __launch_bounds__(NTHR) void k_fused(
    const float* __restrict__ x, const float* __restrict__ w4,
    const float* __restrict__ b4, float* __restrict__ out,
    float* __restrict__ ws)
{
    cg::grid_group grid = cg::this_grid();
    const int t    = threadIdx.x;
    const int blk  = blockIdx.x;
    const int lane = t & 63;
    const int wv   = t >> 6;
    const int row0 = blk * RPB;
    const int c0   = t * CPT;

    float* partials = ws;                          // [NBLK][2][DD]
    float* mu_g     = ws + (size_t)NBLK * 2 * DD;  // [DD]
    float* inv_g    = mu_g + DD;                   // [DD]

    __shared__ float lds_red[NWV][RPB];   // 8 x 32
    __shared__ float lds_s[RPB];          // 32
    __shared__ float lds_st[4][16];       // stats cross-wave (4 active waves)

    // v holds the (normalized) running `out`; starts as x.
    float v[RPB][CPT];
    {
        const float* xp = x + (size_t)row0 * DD + c0;
        #pragma unroll
        for (int r = 0; r < RPB; ++r) {
            *(float4*)&v[r][0] = *(const float4*)xp;
            xp += DD;
        }
    }

    for (int l = 0; l < 4; ++l) {
        // ---- row dot: s[row] = sum_d v[row,d] * w[l,d]  (block-local)
        {
            float wr[CPT];
            *(float4*)&wr[0] = *(const float4*)(w4 + l * DD + c0);
            #pragma unroll
            for (int ch = 0; ch < RPB / 8; ++ch) {
                float p[8];
                #pragma unroll
                for (int i = 0; i < 8; ++i) {
                    const int r = ch * 8 + i;
                    float a = v[r][0] * wr[0];
                    a = fmaf(v[r][1], wr[1], a);
                    a = fmaf(v[r][2], wr[2], a);
                    a = fmaf(v[r][3], wr[3], a);
                    p[i] = a;
                }
                #pragma unroll
                for (int off = 32; off; off >>= 1) {
                    #pragma unroll
                    for (int i = 0; i < 8; ++i)
                        p[i] += __shfl_xor(p[i], off, 64);
                }
                if (lane == 0) {
                    #pragma unroll
                    for (int i = 0; i < 8; ++i) lds_red[wv][ch * 8 + i] = p[i];
                }
            }
        }
        __syncthreads();
        if (t < RPB) {
            float a = 0.f;
            #pragma unroll
            for (int w = 0; w < NWV; ++w) a += lds_red[w][t];
            lds_s[t] = a;
        }
        __syncthreads();

        // ---- update: v = x*s + bias + v
        {
            float bv[CPT];
            *(float4*)&bv[0] = *(const float4*)(b4 + l * DD + c0);
            const float* xp = x + (size_t)row0 * DD + c0;
            #pragma unroll
            for (int r = 0; r < RPB; ++r) {
                const float4 x4 = *(const float4*)xp;
                xp += DD;
                const float sv = lds_s[r];
                v[r][0] = fmaf(x4.x, sv, bv[0] + v[r][0]);
                v[r][1] = fmaf(x4.y, sv, bv[1] + v[r][1]);
                v[r][2] = fmaf(x4.z, sv, bv[2] + v[r][2]);
                v[r][3] = fmaf(x4.w, sv, bv[3] + v[r][3]);
            }
        }

        // ---- column partials (register-only post-pass over v)
        {
            float cs[CPT], cq[CPT];
            #pragma unroll
            for (int j = 0; j < CPT; ++j) { cs[j] = 0.f; cq[j] = 0.f; }
            #pragma unroll
            for (int r = 0; r < RPB; ++r) {
                #pragma unroll
                for (int j = 0; j < CPT; ++j) {
                    cs[j] += v[r][j];
                    cq[j]  = fmaf(v[r][j], v[r][j], cq[j]);
                }
            }
            float* pp = partials + (size_t)blk * 2 * DD;
            *(float4*)(pp + c0)      = *(float4*)&cs[0];
            *(float4*)(pp + DD + c0) = *(float4*)&cq[0];
        }

        grid.sync();

        // ---- stats reduce: block b owns cols [8b, 8b+8)
        {
            const int cb = blk * 8;
            if (t < NBLK) {
                const float* pb = partials + (size_t)t * 2 * DD;
                float a[8], q[8];
                *(float4*)&a[0] = *(const float4*)(pb + cb);
                *(float4*)&a[4] = *(const float4*)(pb + cb + 4);
                *(float4*)&q[0] = *(const float4*)(pb + DD + cb);
                *(float4*)&q[4] = *(const float4*)(pb + DD + cb + 4);
                #pragma unroll
                for (int off = 32; off; off >>= 1) {
                    #pragma unroll
                    for (int j = 0; j < 8; ++j) {
                        a[j] += __shfl_xor(a[j], off, 64);
                        q[j] += __shfl_xor(q[j], off, 64);
                    }
                }
                if (lane == 0) {
                    #pragma unroll
                    for (int j = 0; j < 8; ++j) {
                        lds_st[wv][j]     = a[j];
                        lds_st[wv][8 + j] = q[j];
                    }
                }
            }
            __syncthreads();
            if (t == 0) {
                #pragma unroll
                for (int j = 0; j < 8; ++j) {
                    float A = lds_st[0][j] + lds_st[1][j] + lds_st[2][j] + lds_st[3][j];
                    float Q = lds_st[0][8 + j] + lds_st[1][8 + j] + lds_st[2][8 + j] + lds_st[3][8 + j];
                    const float m  = A / (float)BB;
                    const float va = fmaxf(Q / (float)BB - m * m, 0.f);
                    mu_g[cb + j]  = m;
                    inv_g[cb + j] = rsqrtf(va + BN_EPS);
                }
            }
        }

        grid.sync();

        // ---- normalize registers
        {
            float mv[CPT], iv[CPT];
            *(float4*)&mv[0] = *(const float4*)(mu_g + c0);
            *(float4*)&iv[0] = *(const float4*)(inv_g + c0);
            #pragma unroll
            for (int r = 0; r < RPB; ++r) {
                #pragma unroll
                for (int j = 0; j < CPT; ++j)
                    v[r][j] = (v[r][j] - mv[j]) * iv[j];
            }
        }
    }

    // ---- final store
    {
        float* op = out + (size_t)row0 * DD + c0;
        #pragma unroll
        for (int r = 0; r < RPB; ++r) {
            *(float4*)op = *(float4*)&v[r][0];
            op += DD;
        }
    }
}

// ---------------- fallback: merged per-layer kernel (dot + update + partials) ----
// Block owns 32 whole rows; phase 1: wave per row dot (raw read, L2/L3);
// phase 2: all threads update the 32 rows (raw re-read hits L2), write out
// and per-block column partials. Saves a 64MB pass + 2 launches per layer
// vs the round-1 path.
__global__ __launch_bounds__(512) void k_layer(
    const float* __restrict__ x, const float* __restrict__ raw,
    const float* __restrict__ w, const float* __restrict__ bias,
    const float* __restrict__ mu, const float* __restrict__ inv,
    float* __restrict__ outbuf, float* __restrict__ partials, int use_norm)
{
    const int t    = threadIdx.x;
    const int lane = t & 63;
    const int wv   = t >> 6;
    const int blk  = blockIdx.x;
    const int row0 = blk * 32;

    __shared__ float lds_s[32];

    // phase 1: dots. wave wv handles rows row0 + 4*wv .. +3
    for (int rw = 0; rw < 4; ++rw) {
        const int row = row0 + wv * 4 + rw;
        const float* rp = raw + (size_t)row * DD;
        float acc = 0.f;
        #pragma unroll
        for (int k = 0; k < DD / 256; ++k) {
            const int idx = k * 256 + lane * 4;
            float4 rv  = *(const float4*)(rp + idx);
            const float4 wv4 = *(const float4*)(w + idx);
            if (use_norm) {
                const float4 m  = *(const float4*)(mu + idx);
                const float4 iv = *(const float4*)(inv + idx);
                rv.x = (rv.x - m.x) * iv.x;
                rv.y = (rv.y - m.y) * iv.y;
                rv.z = (rv.z - m.z) * iv.z;
                rv.w = (rv.w - m.w) * iv.w;
            }
            acc += rv.x * wv4.x + rv.y * wv4.y + rv.z * wv4.z + rv.w * wv4.w;
        }
        #pragma unroll
        for (int off = 32; off; off >>= 1) acc += __shfl_xor(acc, off, 64);
        if (lane == 0) lds_s[wv * 4 + rw] = acc;
    }
    __syncthreads();

    // phase 2: update all 32 rows at this thread's 4 columns
    const int c0 = t * 4;
    float4 bv = *(const float4*)(bias + c0);
    float4 m4, iv4;
    if (use_norm) {
        m4  = *(const float4*)(mu + c0);
        iv4 = *(const float4*)(inv + c0);
    } else {
        m4  = make_float4(0.f, 0.f, 0.f, 0.f);
        iv4 = make_float4(1.f, 1.f, 1.f, 1.f);
    }
    float cs[4] = {0.f, 0.f, 0.f, 0.f};
    float cq[4] = {0.f, 0.f, 0.f, 0.f};
    const float* rp = raw + (size_t)row0 * DD + c0;
    const float* xp = x   + (size_t)row0 * DD + c0;
    float*       op = outbuf + (size_t)row0 * DD + c0;
    for (int r = 0; r < 32; ++r) {
        const float4 rv = *(const float4*)rp;
        const float4 x4 = *(const float4*)xp;
        const float  sv = lds_s[r];
        float4 o;
        o.x = fmaf(x4.x, sv, bv.x + (rv.x - m4.x) * iv4.x);
        o.y = fmaf(x4.y, sv, bv.y + (rv.y - m4.y) * iv4.y);
        o.z = fmaf(x4.z, sv, bv.z + (rv.z - m4.z) * iv4.z);
        o.w = fmaf(x4.w, sv, bv.w + (rv.w - m4.w) * iv4.w);
        cs[0] += o.x; cq[0] = fmaf(o.x, o.x, cq[0]);
        cs[1] += o.y; cq[1] = fmaf(o.y, o.y, cq[1]);
        cs[2] += o.z; cq[2] = fmaf(o.z, o.z, cq[2]);
        cs[3] += o.w; cq[3] = fmaf(o.w, o.w, cq[3]);
        *(float4*)op = o;
        rp += DD; xp += DD; op += DD;
    }
    float* pp = partials + (size_t)blk * 2 * DD;
    *(float4*)(pp + c0)      = *(float4*)&cs[0];
    *(float4*)(pp + DD + c0) = *(float4*)&cq[0];
}

__global__ __launch_bounds__(256) void k_stats(
    const float* __restrict__ partials, float* __restrict__ mu, float* __restrict__ inv)
{
    const int col = blockIdx.x * 256 + threadIdx.x;  // grid = DD/256 = 8
    float sum = 0.f, sq = 0.f;
    for (int p = 0; p < 256; ++p) {
        sum += partials[(size_t)p * 2 * DD + col];
        sq  += partials[(size_t)p * 2 * DD + DD + col];
    }
    const float m = sum / (float)BB;
    const float var = fmaxf(sq / (float)BB - m * m, 0.f);
    mu[col]  = m;
    inv[col] = rsqrtf(var + BN_EPS);
}

__global__ __launch_bounds__(256) void k_norm(
    float* __restrict__ out, const float* __restrict__ mu, const float* __restrict__ inv)
{
    const size_t i = ((size_t)blockIdx.x * 256 + threadIdx.x) * 4;
    const int c = (int)(i & (DD - 1));
    float4 v = *(float4*)(out + i);
    const float4 m  = *(const float4*)(mu + c);
    const float4 iv = *(const float4*)(inv + c);
    v.x = (v.x - m.x) * iv.x;
    v.y = (v.y - m.y) * iv.y;
    v.z = (v.z - m.z) * iv.z;
    v.w = (v.w - m.w) * iv.w;
    *(float4*)(out + i) = v;
}

extern "C" void kernel_launch(void* const* d_in, const int* in_sizes, int n_in,
                              void* d_out, int out_size, void* d_ws, size_t ws_size,
                              hipStream_t stream) {
    const float* x  = (const float*)d_in[0];   // [B, D]
    const float* w  = (const float*)d_in[1];   // [4, D]
    const float* bb = (const float*)d_in[2];   // [4, D]
    float* out = (float*)d_out;
    float* ws  = (float*)d_ws;

    // ---- coop path, only if provably co-resident
    bool coop_ok = false;
    const size_t coop_need = ((size_t)NBLK * 2 * DD + 2 * DD) * sizeof(float);
    if (ws_size >= coop_need) {
        int blocks_per_cu = 0;
        hipError_t qe = hipOccupancyMaxActiveBlocksPerMultiprocessor(
            &blocks_per_cu, (const void*)k_fused, NTHR, 0);
        if (qe == hipSuccess && blocks_per_cu >= 1) {   // 256 blocks / 256 CUs
            void* args[] = { (void*)&x, (void*)&w, (void*)&bb, (void*)&out, (void*)&ws };
            hipError_t e = hipLaunchCooperativeKernel((const void*)k_fused, dim3(NBLK),
                                                      dim3(NTHR), args, 0, stream);
            coop_ok = (e == hipSuccess);
        }
    }
    if (coop_ok) return;

    // ---- fallback: merged per-layer path (9 dispatches)
    float* mu_buf   = ws;
    float* inv_buf  = mu_buf + DD;
    float* partials = inv_buf + DD;   // [256][2][DD] = 4 MB

    for (int l = 0; l < 4; ++l) {
        const float* raw = (l == 0) ? x : out;
        k_layer<<<256, 512, 0, stream>>>(x, raw, w + l * DD, bb + l * DD,
                                         mu_buf, inv_buf, out, partials, l != 0);
        k_stats<<<DD / 256, 256, 0, stream>>>(partials, mu_buf, inv_buf);
    }
    k_norm<<<(BB * DD / 4) / 256, 256, 0, stream>>>(out, mu_buf, inv_buf);
}